// Round 6
// baseline (74.057 us; speedup 1.0000x reference)
//
#include <hip/hip_runtime.h>

// ConvDeepSet: B=8, N_IN=1024, N_OUT=4096, OUT_CHANNELS=64
//
// dens[b,m] = sum_n exp(k0*d(n,m)), conv[b,m] = sum_n y[n] exp(k1*d(n,m))
// out[b,m,o] = dens*W[o,0] + (conv/(dens+1e-8))*W[o,1] + b[o]
// k = -0.5*exp(-2*sigma)*log2(e); exp via v_exp_f32 (exp2 domain).
//
// R5 post-mortem: inner loop was LDS-return-bus bound (broadcast b128 still
// moves 1024 B/wave-read at ~128 B/cyc; 1 pair/read -> 6.8us LDS floor).
// Fix: n-records are WAVE-UNIFORM -> read raw x,y straight from global with
// wave-uniform addresses (wave idx via readfirstlane so the compiler can
// prove uniformity and select s_load / scalar cache; VMEM fallback is one
// coalesced L1-hit per load). s0 folds into the fma: dx = fma(x0,s0,-s0*t0),
// arg = fma(dx,-dx,-dy*dy): 6 VALU + 1 trans per pair, <=1 SGPR per instr.
// No staging, no pre-loop barrier; LDS only for the 16-wave reduction.
//
// Fast path r = k1/k0 == 1 (actual data: sigma[0]==sigma[1]): one exp/pair.
//
// Block: 1024 thr = 16 waves, 64 m/block (1 m/lane), n split 16 ways
// (64 n = 32 float4 x + 32 float2 y per wave). Grid: 8 x 64 = 512 blocks
// = 2 blocks/CU -> 8 waves/SIMD.

#define OUTC 64
#define MB   64
#define NW   16

__global__ __launch_bounds__(1024, 8) void convdeepset_kernel(
    const float* __restrict__ x,     // [B,1024,2]
    const float* __restrict__ y,     // [B,1024]
    const float* __restrict__ t,     // [B,4096,2]
    const float* __restrict__ sigma, // [2]
    const float* __restrict__ W,     // [64,2]
    const float* __restrict__ bias,  // [64]
    float* __restrict__ out)         // [B,4096,64]
{
    __shared__ float dens_part[NW*MB];   // 4 KB
    __shared__ float conv_part[NW*MB];   // 4 KB
    __shared__ float sums[2*MB];
    __shared__ float dens_tot[MB];
    __shared__ float ratio[MB];

    const int tid = threadIdx.x;
    const int b   = blockIdx.x >> 6;         // 64 m-tiles per batch
    const int m0  = (blockIdx.x & 63) * MB;

    const float log2e = 1.44269504088896340736f;
    const float k0 = -0.5f * __expf(-2.0f * sigma[0]) * log2e;
    const float k1 = -0.5f * __expf(-2.0f * sigma[1]) * log2e;
    const float s0 = sqrtf(-k0);
    const float r  = k1 / k0;                // conv exponent = r * arg

    // wave index made provably uniform -> scalar (s_load) selection for the
    // n-chunk loads below.
    const int wave = __builtin_amdgcn_readfirstlane(tid >> 6);
    const int lane = tid & 63;

    const float2 tv = ((const float2*)(t + ((size_t)b * 4096 + m0) * 2))[lane];
    const float nu = -(tv.x * s0);           // dx = fma(x0, s0, nu)
    const float nv = -(tv.y * s0);           // dy = fma(x1, s0, nv)

    // Wave-uniform n-chunk pointers: 64 n = 32 float4 of x, 32 float2 of y.
    const float4* xq = (const float4*)(x + (size_t)b * 2048) + (wave << 5);
    const float2* yq = (const float2*)(y + (size_t)b * 1024) + (wave << 5);

    float dacc = 0.f, cacc = 0.f;

    if (r == 1.0f) {
        #pragma unroll 4
        for (int i = 0; i < 32; ++i) {
            const float4 xx = xq[i];         // (x0a,x1a,x0b,x1b) uniform
            const float2 yv = yq[i];         // (ya,yb)            uniform
            {
                float dx = fmaf(xx.x, s0, nu);
                float dy = fmaf(xx.y, s0, nv);
                float e  = __builtin_amdgcn_exp2f(fmaf(dx, -dx, -(dy * dy)));
                dacc += e;
                cacc = fmaf(yv.x, e, cacc);
            }
            {
                float dx = fmaf(xx.z, s0, nu);
                float dy = fmaf(xx.w, s0, nv);
                float e  = __builtin_amdgcn_exp2f(fmaf(dx, -dx, -(dy * dy)));
                dacc += e;
                cacc = fmaf(yv.y, e, cacc);
            }
        }
    } else {
        #pragma unroll 2
        for (int i = 0; i < 32; ++i) {
            const float4 xx = xq[i];
            const float2 yv = yq[i];
            {
                float dx  = fmaf(xx.x, s0, nu);
                float dy  = fmaf(xx.y, s0, nv);
                float arg = fmaf(dx, -dx, -(dy * dy));
                dacc += __builtin_amdgcn_exp2f(arg);
                cacc = fmaf(yv.x, __builtin_amdgcn_exp2f(arg * r), cacc);
            }
            {
                float dx  = fmaf(xx.z, s0, nu);
                float dy  = fmaf(xx.w, s0, nv);
                float arg = fmaf(dx, -dx, -(dy * dy));
                dacc += __builtin_amdgcn_exp2f(arg);
                cacc = fmaf(yv.y, __builtin_amdgcn_exp2f(arg * r), cacc);
            }
        }
    }

    dens_part[wave * MB + lane] = dacc;
    conv_part[wave * MB + lane] = cacc;
    __syncthreads();

    // Cross-wave reduce: 128 threads, one (channel, m) each, 16 partials.
    if (tid < 2 * MB) {
        const int m = tid & (MB - 1);
        const float* src = (tid < MB) ? dens_part : conv_part;
        float s = 0.f;
        #pragma unroll
        for (int w = 0; w < NW; ++w) s += src[w * MB + m];
        sums[tid] = s;
    }
    __syncthreads();
    if (tid < MB) {
        float dt = sums[tid];
        dens_tot[tid] = dt;
        ratio[tid]    = sums[MB + tid] / (dt + 1e-8f);
    }
    __syncthreads();

    // Epilogue: 64 m x 64 o; lane->o (coalesced), 16 groups x 4 m each.
    const int o = tid & 63;
    const int g = tid >> 6;
    const float w0 = W[o * 2 + 0];
    const float w1 = W[o * 2 + 1];
    const float bo = bias[o];
    float* outb = out + ((size_t)b * 4096 + m0) * OUTC;
    #pragma unroll
    for (int i = 0; i < 4; ++i) {
        int mm = g * 4 + i;
        outb[mm * OUTC + o] = fmaf(dens_tot[mm], w0, fmaf(ratio[mm], w1, bo));
    }
}

extern "C" void kernel_launch(void* const* d_in, const int* in_sizes, int n_in,
                              void* d_out, int out_size, void* d_ws, size_t ws_size,
                              hipStream_t stream) {
    const float* x     = (const float*)d_in[0];
    const float* y     = (const float*)d_in[1];
    const float* t     = (const float*)d_in[2];
    const float* sigma = (const float*)d_in[3];
    const float* W     = (const float*)d_in[4];
    const float* bias  = (const float*)d_in[5];
    float* out = (float*)d_out;

    // 8 batches x 64 m-tiles = 512 blocks (2/CU), 1024 threads each.
    convdeepset_kernel<<<dim3(512), dim3(1024), 0, stream>>>(
        x, y, t, sigma, W, bias, out);
}

// Round 7
// 72.503 us; speedup vs baseline: 1.0214x; 1.0214x over previous
//
#include <hip/hip_runtime.h>

// ConvDeepSet: B=8, N_IN=1024, N_OUT=4096, OUT_CHANNELS=64
//
// dens[b,m] = sum_n exp(k0*d(n,m)), conv[b,m] = sum_n y[n] exp(k1*d(n,m))
// out[b,m,o] = dens*W[o,0] + (conv/(dens+1e-8))*W[o,1] + b[o]
//
// Issue model (validated R2/R5/R6): VALU(2cyc) and v_exp_f32(8cyc, quarter
// rate) share the SIMD issue port. R7 cuts both terms:
//  - M=2 target points per lane; LDS record pk[n]=(2sx,2sy,q=-|sx|^2,y) so
//    ONE broadcast ds_read_b128 feeds 2 pairs -> LDS 8192 cyc/CU (3.4us).
//  - args for both m computed as float2 ext-vector -> v_pk_{add,fma}_f32:
//    per 2 pairs = 5 pk (10 cyc) + 2 exp (16 cyc) = 13 cyc/group (was 18).
//    arg_m = (q + cm_m) + p.x*u_m + p.y*v_m  (<=0 always; cm inside exp).
// Fast path r = k1/k0 == 1 (actual data): one exp per pair.
//
// Block: 1024 thr = 16 waves, MB=128 m (lane m and m+64), n-split 16
// (64 n/wave). Grid: 8 x 32 = 256 blocks = 1/CU, 4 waves/SIMD.

#define OUTC 64
#define MB   128
#define NW   16

typedef __attribute__((ext_vector_type(2))) float f32x2;

__global__ __launch_bounds__(1024, 4) void convdeepset_kernel(
    const float* __restrict__ x,     // [B,1024,2]
    const float* __restrict__ y,     // [B,1024]
    const float* __restrict__ t,     // [B,4096,2]
    const float* __restrict__ sigma, // [2]
    const float* __restrict__ W,     // [64,2]
    const float* __restrict__ bias,  // [64]
    float* __restrict__ out)         // [B,4096,64]
{
    __shared__ float4 pk[1024];          // 16 KB: (2sx, 2sy, q, y)
    __shared__ float  dens_part[NW*MB];  // 8 KB
    __shared__ float  conv_part[NW*MB];  // 8 KB
    __shared__ float  sums[2*MB];
    __shared__ float  dens_tot[MB];
    __shared__ float  ratio[MB];

    const int tid = threadIdx.x;
    const int b   = blockIdx.x >> 5;         // 32 m-tiles per batch
    const int m0  = (blockIdx.x & 31) * MB;

    const float log2e = 1.44269504088896340736f;
    const float k0 = -0.5f * __expf(-2.0f * sigma[0]) * log2e;
    const float k1 = -0.5f * __expf(-2.0f * sigma[1]) * log2e;
    const float s0 = sqrtf(-k0);
    const float r  = k1 / k0;                // conv exponent = r * arg

    // Stage: each thread builds one pk record (coalesced float2 + float).
    {
        const float2 xv = ((const float2*)(x + (size_t)b * 2048))[tid];
        const float  yv = y[(size_t)b * 1024 + tid];
        const float sx = xv.x * s0, sy = xv.y * s0;
        pk[tid] = make_float4(sx + sx, sy + sy,
                              -fmaf(sx, sx, sy * sy), yv);
    }

    const int wave = tid >> 6;
    const int lane = tid & 63;
    const float2* tg = (const float2*)(t + ((size_t)b * 4096 + m0) * 2);
    const float2 ta = tg[lane];
    const float2 tb = tg[64 + lane];
    f32x2 u2, v2, cm2;
    u2.x = ta.x * s0;  u2.y = tb.x * s0;
    v2.x = ta.y * s0;  v2.y = tb.y * s0;
    cm2.x = -fmaf(u2.x, u2.x, v2.x * v2.x);
    cm2.y = -fmaf(u2.y, u2.y, v2.y * v2.y);

    __syncthreads();

    f32x2 dacc = {0.f, 0.f}, cacc = {0.f, 0.f};
    const int ibeg = wave * 64;              // 64 n per wave

    if (r == 1.0f) {
        #pragma unroll 4
        for (int i = ibeg; i < ibeg + 64; ++i) {
            const float4 p = pk[i];          // wave-broadcast b128
            f32x2 arg = cm2 + p.z;                               // pk_add
            arg = __builtin_elementwise_fma((f32x2)p.x, u2, arg); // pk_fma
            arg = __builtin_elementwise_fma((f32x2)p.y, v2, arg); // pk_fma
            f32x2 e;
            e.x = __builtin_amdgcn_exp2f(arg.x);
            e.y = __builtin_amdgcn_exp2f(arg.y);
            dacc += e;                                            // pk_add
            cacc = __builtin_elementwise_fma((f32x2)p.w, e, cacc);// pk_fma
        }
    } else {
        #pragma unroll 2
        for (int i = ibeg; i < ibeg + 64; ++i) {
            const float4 p = pk[i];
            f32x2 arg = cm2 + p.z;
            arg = __builtin_elementwise_fma((f32x2)p.x, u2, arg);
            arg = __builtin_elementwise_fma((f32x2)p.y, v2, arg);
            f32x2 e, er;
            e.x  = __builtin_amdgcn_exp2f(arg.x);
            e.y  = __builtin_amdgcn_exp2f(arg.y);
            er.x = __builtin_amdgcn_exp2f(arg.x * r);
            er.y = __builtin_amdgcn_exp2f(arg.y * r);
            dacc += e;
            cacc = __builtin_elementwise_fma((f32x2)p.w, er, cacc);
        }
    }

    dens_part[wave * MB + lane]      = dacc.x;
    dens_part[wave * MB + 64 + lane] = dacc.y;
    conv_part[wave * MB + lane]      = cacc.x;
    conv_part[wave * MB + 64 + lane] = cacc.y;
    __syncthreads();

    // Cross-wave reduce: 256 threads, one (channel, m) each, 16 partials.
    if (tid < 2 * MB) {
        const int m = tid & (MB - 1);
        const float* src = (tid < MB) ? dens_part : conv_part;
        float s = 0.f;
        #pragma unroll
        for (int w = 0; w < NW; ++w) s += src[w * MB + m];
        sums[tid] = s;
    }
    __syncthreads();
    if (tid < MB) {
        float dt = sums[tid];
        dens_tot[tid] = dt;
        ratio[tid]    = sums[MB + tid] / (dt + 1e-8f);
    }
    __syncthreads();

    // Epilogue: 128 m x 64 o; lane->o (coalesced), 16 groups x 8 m each.
    const int o = tid & 63;
    const int g = tid >> 6;
    const float w0 = W[o * 2 + 0];
    const float w1 = W[o * 2 + 1];
    const float bo = bias[o];
    float* outb = out + ((size_t)b * 4096 + m0) * OUTC;
    #pragma unroll
    for (int i = 0; i < 8; ++i) {
        int mm = g * 8 + i;
        outb[mm * OUTC + o] = fmaf(dens_tot[mm], w0, fmaf(ratio[mm], w1, bo));
    }
}

extern "C" void kernel_launch(void* const* d_in, const int* in_sizes, int n_in,
                              void* d_out, int out_size, void* d_ws, size_t ws_size,
                              hipStream_t stream) {
    const float* x     = (const float*)d_in[0];
    const float* y     = (const float*)d_in[1];
    const float* t     = (const float*)d_in[2];
    const float* sigma = (const float*)d_in[3];
    const float* W     = (const float*)d_in[4];
    const float* bias  = (const float*)d_in[5];
    float* out = (float*)d_out;

    // 8 batches x 32 m-tiles = 256 blocks (1/CU), 1024 threads each.
    convdeepset_kernel<<<dim3(256), dim3(1024), 0, stream>>>(
        x, y, t, sigma, W, bias, out);
}